// Round 5
// baseline (558.612 us; speedup 1.0000x reference)
//
#include <hip/hip_runtime.h>
#include <hip/hip_bf16.h>
#include <stdint.h>

using sh8   = __attribute__((ext_vector_type(8))) short;
using f32x4 = __attribute__((ext_vector_type(4))) float;

#define MFMA16(a, b, c) __builtin_amdgcn_mfma_f32_16x16x32_bf16(a, b, c, 0, 0, 0)
#define EXP2F(x) __builtin_amdgcn_exp2f(x)

static constexpr int BB = 32, SS = 577, HH = 16;
static constexpr int MM = BB * SS;     // 18464 rows (b,s)
static constexpr int SPAD = 640;       // padded S for V^T buffer
// attention scale folded into Wq, in log2 domain: D^-0.5 * log2(e)
static constexpr float QSCALE = 0.18033688011112042f;

__device__ __forceinline__ ushort f2b(float f) {
  union { float f; uint32_t u; } v{f};
  uint32_t r = v.u + 0x7FFFu + ((v.u >> 16) & 1u);   // RNE
  return (ushort)(r >> 16);
}

#if __has_builtin(__builtin_amdgcn_cvt_pk_bf16_f32)
typedef __attribute__((ext_vector_type(2))) __bf16 bf16x2_t;
__device__ __forceinline__ uint32_t pk_bf16(float a, float b) {
  union { bf16x2_t v; uint32_t u; } c;
  c.v = __builtin_amdgcn_cvt_pk_bf16_f32(a, b);
  return c.u;
}
#else
__device__ __forceinline__ uint32_t pk_bf16(float a, float b) {
  return (uint32_t)f2b(a) | ((uint32_t)f2b(b) << 16);
}
#endif

// async global->LDS, 16B per lane. LDS dest is wave-uniform base + lane*16.
__device__ __forceinline__ void gld16(const ushort* g, ushort* l) {
  __builtin_amdgcn_global_load_lds(
      (const __attribute__((address_space(1))) uint32_t*)g,
      (__attribute__((address_space(3))) uint32_t*)l, 16, 0, 0);
}

// ---------------- converts ----------------
__global__ __launch_bounds__(256)
void convert_f32_bf16_v4(const float* __restrict__ in, ushort* __restrict__ out, int n4) {
  int i = blockIdx.x * 256 + threadIdx.x;
  const int stride = gridDim.x * 256;
  for (; i < n4; i += stride) {
    const float4 f = ((const float4*)in)[i];
    ushort4 u;
    u.x = f2b(f.x); u.y = f2b(f.y); u.z = f2b(f.z); u.w = f2b(f.w);
    ((ushort4*)out)[i] = u;
  }
}

// Wt[n][k], n = sel*1024 + h*64 + d  (B^T layout), k = e.  LDS-tiled transpose.
// Wq gets QSCALE folded in. grid (16 ktiles, 48 sel*h).
__global__ __launch_bounds__(256)
void convert_wqkv(const float* __restrict__ Wq, const float* __restrict__ Wk,
                  const float* __restrict__ Wv, ushort* __restrict__ Wt) {
  __shared__ ushort T[64 * 72];
  const int tid = threadIdx.x;
  const int kt = blockIdx.x, sh = blockIdx.y;
  const int sel = sh >> 4, h = sh & 15;
  const float* W = (sel == 0) ? Wq : ((sel == 1) ? Wk : Wv);
  const float qs = (sel == 0) ? QSCALE : 1.0f;
  const int rr = tid >> 4;          // 0..15 (k' row)
  const int rc = (tid & 15) * 4;    // d col (float4)
#pragma unroll
  for (int p = 0; p < 64; p += 16) {
    const float4 f = *(const float4*)(W + (size_t)h * 65536 + (size_t)(kt * 64 + p + rr) * 64 + rc);
    ushort4 u;
    u.x = f2b(f.x * qs); u.y = f2b(f.y * qs); u.z = f2b(f.z * qs); u.w = f2b(f.w * qs);
    *(ushort4*)&T[(p + rr) * 72 + rc] = u;
  }
  __syncthreads();
  const int dd = tid >> 2;          // 0..63 (d)
  const int c16 = (tid & 3) * 16;   // k' base
  sh8 v0, v1;
#pragma unroll
  for (int j = 0; j < 8; j++) v0[j] = (short)T[(c16 + j) * 72 + dd];
#pragma unroll
  for (int j = 0; j < 8; j++) v1[j] = (short)T[(c16 + 8 + j) * 72 + dd];
  ushort* op = Wt + ((size_t)sel * 1024 + h * 64 + dd) * 1024 + kt * 64 + c16;
  *(sh8*)op = v0;
  *(sh8*)(op + 8) = v1;
}

// ---------------- GEMM: 128x256 block, 64x128 wave tile, BK=64, XOR-swizzled LDS.
// C = A * Bt^T, C^T epilogue. MODE 0: store bf16.  MODE 1: store f32 + bias.
// N must be a multiple of 256.
template <int MODE>
__global__ __launch_bounds__(256)
void gemm_bt(const ushort* __restrict__ A, const ushort* __restrict__ Bt,
             ushort* __restrict__ Cb, float* __restrict__ Cf,
             const float* __restrict__ bias, int M, int N, int K) {
  __shared__ ushort Al[128 * 64];   // 16 KB
  __shared__ ushort Bl[256 * 64];   // 32 KB
  const int tid = threadIdx.x;
  const int lane = tid & 63, w = tid >> 6;
  const int l15 = lane & 15, quad = lane >> 4;
  const int wm = (w >> 1) * 64, wn = (w & 1) * 128;
  const int m0 = blockIdx.y * 128, n0 = blockIdx.x * 256;

  f32x4 acc[4][8];
#pragma unroll
  for (int i = 0; i < 4; i++)
#pragma unroll
    for (int j = 0; j < 8; j++) acc[i][j] = f32x4{0.f, 0.f, 0.f, 0.f};

  // staging: unit u covers LDS ushorts [u*8, u*8+8); row=u>>3, cc=u&7 (swizzled)
  const int rbase = tid >> 3;                         // 0..31
  const int swzc = ((tid & 7) ^ (rbase & 7)) * 8;     // swizzled source col (ushorts)
  const ushort* Ag[4]; const ushort* Bg[8];
  ushort* lA[4]; ushort* lB[8];
#pragma unroll
  for (int i = 0; i < 4; i++) {
    Ag[i] = A + (size_t)min(m0 + i * 32 + rbase, M - 1) * K + swzc;
    lA[i] = &Al[(i * 256 + tid) * 8];
  }
#pragma unroll
  for (int i = 0; i < 8; i++) {
    Bg[i] = Bt + (size_t)(n0 + i * 32 + rbase) * K + swzc;
    lB[i] = &Bl[(i * 256 + tid) * 8];
  }
  const int swz = l15 & 7;
  const int ck0 = (quad ^ swz) * 8;                   // k-chunk (kk=0)
  const int ck1 = ((quad + 4) ^ swz) * 8;             // k-chunk (kk=1)

  for (int k0 = 0; k0 < K; k0 += 64) {
    __syncthreads();
#pragma unroll
    for (int i = 0; i < 4; i++) gld16(Ag[i] + k0, lA[i]);
#pragma unroll
    for (int i = 0; i < 8; i++) gld16(Bg[i] + k0, lB[i]);
    __syncthreads();
#pragma unroll
    for (int kk = 0; kk < 2; kk++) {
      const int ck = kk ? ck1 : ck0;
      sh8 af[4], bf[8];
#pragma unroll
      for (int i = 0; i < 4; i++) af[i] = *(const sh8*)&Al[(wm + i * 16 + l15) * 64 + ck];
#pragma unroll
      for (int j = 0; j < 8; j++) bf[j] = *(const sh8*)&Bl[(wn + j * 16 + l15) * 64 + ck];
      // C^T: D[m=Ccol][n=Crow]
#pragma unroll
      for (int i = 0; i < 4; i++)
#pragma unroll
        for (int j = 0; j < 8; j++) acc[i][j] = MFMA16(bf[j], af[i], acc[i][j]);
    }
  }

  // C^T epilogue: lane holds C-row = m0+wm+i*16+l15, C-cols n0+wn+j*16+quad*4 .. +3
#pragma unroll
  for (int i = 0; i < 4; i++) {
    const int row = m0 + wm + i * 16 + l15;
    const bool ok = row < M;
#pragma unroll
    for (int j = 0; j < 8; j++) {
      const int col0 = n0 + wn + j * 16 + quad * 4;
      if (MODE == 0) {
        uint2 pk;
        pk.x = pk_bf16(acc[i][j][0], acc[i][j][1]);
        pk.y = pk_bf16(acc[i][j][2], acc[i][j][3]);
        if (ok) *(uint2*)&Cb[(size_t)row * N + col0] = pk;
      } else {
        const float4 b4 = *(const float4*)&bias[col0];
        float4 v;
        v.x = acc[i][j][0] + b4.x; v.y = acc[i][j][1] + b4.y;
        v.z = acc[i][j][2] + b4.z; v.w = acc[i][j][3] + b4.w;
        if (ok) *(float4*)&Cf[(size_t)row * N + col0] = v;
      }
    }
  }
}

// ---------------- transpose V: QKV[.,2048+h*64+d] -> Vt[(bh*64+d)][s], zero-padded ----------------
__global__ __launch_bounds__(256)
void transpose_v(const ushort* __restrict__ QKV, ushort* __restrict__ Vtg) {
  __shared__ ushort T[64 * 72];
  const int tid = threadIdx.x;
  const int st = blockIdx.x, bh = blockIdx.y;
  const int b = bh >> 4, h = bh & 15;
  const int sr = tid >> 3;          // 0..31
  const int sc = (tid & 7) * 8;     // d-chunk
#pragma unroll
  for (int p = 0; p < 64; p += 32) {
    const int s = st * 64 + p + sr;
    uint4 d = uint4{0u, 0u, 0u, 0u};
    if (s < SS) d = *(const uint4*)(QKV + ((size_t)b * SS + s) * 3072 + 2048 + h * 64 + sc);
    *(uint4*)&T[(p + sr) * 72 + sc] = d;
  }
  __syncthreads();
  const int dd = tid >> 2;          // 0..63
  const int s16 = (tid & 3) * 16;
  sh8 v0, v1;
#pragma unroll
  for (int j = 0; j < 8; j++) v0[j] = (short)T[(s16 + j) * 72 + dd];
#pragma unroll
  for (int j = 0; j < 8; j++) v1[j] = (short)T[(s16 + 8 + j) * 72 + dd];
  ushort* outp = Vtg + ((size_t)bh * 64 + dd) * SPAD + st * 64 + s16;
  *(sh8*)outp = v0;
  *(sh8*)(outp + 8) = v1;
}

// ---------------- flash attention (one-pass softmax, 32 q-rows/wave) -------------
// grid: (5 qblocks of 128, 512 bh). K/V staged via gld16 into swizzled 64-stride
// tiles; each wave reuses K/V frags across 2 q-groups of 16.
// S^T = K·Q^T; O^T = V^T·P^T; l = ones·P^T (all MFMA, no shuffles).
__global__ __launch_bounds__(256)
void flash_attn(const ushort* __restrict__ QKV, const ushort* __restrict__ Vtg,
                ushort* __restrict__ Ob) {
  __shared__ ushort Kl[64 * 64];    // row = kpos, chunk-swizzled
  __shared__ ushort Vl[64 * 64];    // row = d,    chunk-swizzled
  __shared__ ushort Pl[128 * 72];   // row = q (wave-local 32 rows), col = kpos
  const int tid = threadIdx.x;
  const int lane = tid & 63, w = tid >> 6;
  const int l15 = lane & 15, quad = lane >> 4;
  const int qb = blockIdx.x, bh = blockIdx.y;
  const int b = bh >> 4, h = bh & 15;

  sh8 qf[2][2];
#pragma unroll
  for (int g = 0; g < 2; g++) {
    const int qr = qb * 128 + w * 32 + g * 16 + l15;
    const ushort* qrow = QKV + ((size_t)b * SS + min(qr, SS - 1)) * 3072 + h * 64;
    qf[g][0] = *(const sh8*)(qrow + quad * 8);
    qf[g][1] = *(const sh8*)(qrow + 32 + quad * 8);
  }

  sh8 ones;
#pragma unroll
  for (int j = 0; j < 8; j++) ones[j] = (short)0x3F80;   // bf16 1.0

  f32x4 o[2][4];
  f32x4 acc_l[2];
#pragma unroll
  for (int g = 0; g < 2; g++) {
    acc_l[g] = f32x4{0.f, 0.f, 0.f, 0.f};
#pragma unroll
    for (int t = 0; t < 4; t++) o[g][t] = f32x4{0.f, 0.f, 0.f, 0.f};
  }

  // staging: 2 gld16 per matrix; unit u = i*256+tid, row=u>>3, cc=u&7, swizzled source
  const int r0 = tid >> 3;                           // 0..31
  const int swzs = ((tid & 7) ^ (r0 & 7)) * 8;
  const ushort* Kg = QKV + (size_t)b * SS * 3072 + 1024 + h * 64 + swzs;
  const ushort* Vg0 = Vtg + ((size_t)bh * 64 + r0) * SPAD + swzs;
  const ushort* Vg1 = Vtg + ((size_t)bh * 64 + 32 + r0) * SPAD + swzs;
  ushort* lK0 = &Kl[tid * 8];
  ushort* lK1 = &Kl[(256 + tid) * 8];
  ushort* lV0 = &Vl[tid * 8];
  ushort* lV1 = &Vl[(256 + tid) * 8];

  const int swz = l15 & 7;
  const int ca0 = (quad ^ swz) * 8;
  const int ca1 = ((quad + 4) ^ swz) * 8;
  ushort* plw[2] = { &Pl[(w * 32 + l15) * 72], &Pl[(w * 32 + 16 + l15) * 72] };

  for (int kt = 0; kt < 10; kt++) {
    const int kb = kt * 64;
    __syncthreads();
    gld16(Kg + (size_t)min(kb + r0, SS - 1) * 3072, lK0);
    gld16(Kg + (size_t)min(kb + 32 + r0, SS - 1) * 3072, lK1);
    gld16(Vg0 + kb, lV0);
    gld16(Vg1 + kb, lV1);
    __syncthreads();

#pragma unroll
    for (int tn = 0; tn < 4; tn++) {
      const int kr = tn * 16 + l15;
      const sh8 k0 = *(const sh8*)&Kl[kr * 64 + ca0];
      const sh8 k1 = *(const sh8*)&Kl[kr * 64 + ca1];
#pragma unroll
      for (int g = 0; g < 2; g++) {
        f32x4 s = f32x4{0.f, 0.f, 0.f, 0.f};
        s = MFMA16(k0, qf[g][0], s);      // S^T: row=kpos=tn*16+quad*4+r, col=q=l15
        s = MFMA16(k1, qf[g][1], s);
        if (kt == 9) {                    // kb=576: only kpos-local 0 is valid
#pragma unroll
          for (int r = 0; r < 4; r++)
            if ((tn * 16 + quad * 4 + r) != 0) s[r] = -1e30f;
        }
        uint2 pp;
        pp.x = pk_bf16(EXP2F(s[0]), EXP2F(s[1]));
        pp.y = pk_bf16(EXP2F(s[2]), EXP2F(s[3]));
        *(uint2*)(plw[g] + tn * 16 + quad * 4) = pp;
      }
    }
    // wave-local P rows: no barrier needed between write and read
    sh8 pa[2][2];
#pragma unroll
    for (int g = 0; g < 2; g++) {
      pa[g][0] = *(const sh8*)(plw[g] + quad * 8);     // B: n=q=l15, k=kpos
      pa[g][1] = *(const sh8*)(plw[g] + 32 + quad * 8);
      acc_l[g] = MFMA16(ones, pa[g][0], acc_l[g]);
      acc_l[g] = MFMA16(ones, pa[g][1], acc_l[g]);
    }
#pragma unroll
    for (int t = 0; t < 4; t++) {
      const int vr = t * 16 + l15;
      const sh8 v0 = *(const sh8*)&Vl[vr * 64 + ca0];  // A: m=d, k=kpos
      const sh8 v1 = *(const sh8*)&Vl[vr * 64 + ca1];
#pragma unroll
      for (int g = 0; g < 2; g++) {
        o[g][t] = MFMA16(v0, pa[g][0], o[g][t]);       // O^T: row=d, col=q=l15
        o[g][t] = MFMA16(v1, pa[g][1], o[g][t]);
      }
    }
  }

#pragma unroll
  for (int g = 0; g < 2; g++) {
    const float inv = 1.0f / acc_l[g][0];
    const int s = qb * 128 + w * 32 + g * 16 + l15;
    if (s < SS) {
      ushort* op = Ob + ((size_t)b * SS + s) * 1024 + h * 64 + quad * 4;
#pragma unroll
      for (int t = 0; t < 4; t++) {
        uint2 ov;
        ov.x = pk_bf16(o[g][t][0] * inv, o[g][t][1] * inv);
        ov.y = pk_bf16(o[g][t][2] * inv, o[g][t][3] * inv);
        *(uint2*)(op + t * 16) = ov;
      }
    }
  }
}

// ---------------- launch ----------------
extern "C" void kernel_launch(void* const* d_in, const int* in_sizes, int n_in,
                              void* d_out, int out_size, void* d_ws, size_t ws_size,
                              hipStream_t stream) {
  const float* x  = (const float*)d_in[0];
  const float* Wq = (const float*)d_in[1];
  const float* Wk = (const float*)d_in[2];
  const float* Wv = (const float*)d_in[3];
  const float* Wo = (const float*)d_in[4];
  const float* bo = (const float*)d_in[5];
  float* out = (float*)d_out;

  // workspace layout (bf16 elements); Ob reuses Xb (dead after GEMM1)
  ushort* Xb  = (ushort*)d_ws;                      // MM*1024
  ushort* Wt  = Xb  + (size_t)MM * 1024;            // 3072*1024
  ushort* Wob = Wt  + (size_t)3072 * 1024;          // 1024*1024
  ushort* QKV = Wob + (size_t)1024 * 1024;          // MM*3072
  ushort* Vtg = QKV + (size_t)MM * 3072;            // 512*64*640
  ushort* Ob  = Xb;

  convert_f32_bf16_v4<<<4096, 256, 0, stream>>>(x, Xb, MM * 1024 / 4);
  convert_wqkv<<<dim3(16, 48), 256, 0, stream>>>(Wq, Wk, Wv, Wt);
  convert_f32_bf16_v4<<<1024, 256, 0, stream>>>(Wo, Wob, 1024 * 1024 / 4);
  gemm_bt<0><<<dim3(12, 145), 256, 0, stream>>>(Xb, Wt, QKV, nullptr, nullptr, MM, 3072, 1024);
  transpose_v<<<dim3(10, 512), 256, 0, stream>>>(QKV, Vtg);
  flash_attn<<<dim3(5, 512), 256, 0, stream>>>(QKV, Vtg, Ob);
  gemm_bt<1><<<dim3(4, 145), 256, 0, stream>>>(Ob, Wob, nullptr, out, bo, MM, 1024, 1024);
}

// Round 6
// 442.876 us; speedup vs baseline: 1.2613x; 1.2613x over previous
//
#include <hip/hip_runtime.h>
#include <hip/hip_bf16.h>
#include <stdint.h>

using sh8    = __attribute__((ext_vector_type(8))) short;
using f32x4  = __attribute__((ext_vector_type(4))) float;
using f32x16 = __attribute__((ext_vector_type(16))) float;

#define MFMA16(a, b, c) __builtin_amdgcn_mfma_f32_16x16x32_bf16(a, b, c, 0, 0, 0)
#define MFMA32(a, b, c) __builtin_amdgcn_mfma_f32_32x32x16_bf16(a, b, c, 0, 0, 0)
#define EXP2F(x) __builtin_amdgcn_exp2f(x)

static constexpr int BB = 32, SS = 577, HH = 16;
static constexpr int MM = BB * SS;     // 18464 rows (b,s)
static constexpr int SPAD = 640;       // padded S for V^T buffer
// attention scale folded into Wq, in log2 domain: D^-0.5 * log2(e)
static constexpr float QSCALE = 0.18033688011112042f;

__device__ __forceinline__ ushort f2b(float f) {
  union { float f; uint32_t u; } v{f};
  uint32_t r = v.u + 0x7FFFu + ((v.u >> 16) & 1u);   // RNE
  return (ushort)(r >> 16);
}

#if __has_builtin(__builtin_amdgcn_cvt_pk_bf16_f32)
typedef __attribute__((ext_vector_type(2))) __bf16 bf16x2_t;
__device__ __forceinline__ uint32_t pk_bf16(float a, float b) {
  union { bf16x2_t v; uint32_t u; } c;
  c.v = __builtin_amdgcn_cvt_pk_bf16_f32(a, b);
  return c.u;
}
#else
__device__ __forceinline__ uint32_t pk_bf16(float a, float b) {
  return (uint32_t)f2b(a) | ((uint32_t)f2b(b) << 16);
}
#endif

// async global->LDS, 16B per lane. LDS dest is wave-uniform base + lane*16.
__device__ __forceinline__ void gld16(const ushort* g, ushort* l) {
  __builtin_amdgcn_global_load_lds(
      (const __attribute__((address_space(1))) uint32_t*)g,
      (__attribute__((address_space(3))) uint32_t*)l, 16, 0, 0);
}

// ---------------- converts (x and Wo fused in one launch) ----------------
__global__ __launch_bounds__(256)
void convert2_f32_bf16(const float* __restrict__ a, ushort* __restrict__ oa, int na4,
                       const float* __restrict__ b, ushort* __restrict__ ob, int nb4) {
  const int total = na4 + nb4;
  const int stride = gridDim.x * 256;
  for (int i = blockIdx.x * 256 + threadIdx.x; i < total; i += stride) {
    const float4 f = (i < na4) ? ((const float4*)a)[i] : ((const float4*)b)[i - na4];
    ushort4 u;
    u.x = f2b(f.x); u.y = f2b(f.y); u.z = f2b(f.z); u.w = f2b(f.w);
    if (i < na4) ((ushort4*)oa)[i] = u;
    else         ((ushort4*)ob)[i - na4] = u;
  }
}

// Wt[n][k], n = sel*1024 + h*64 + d  (B^T layout), k = e.  LDS-tiled transpose.
// Wq gets QSCALE folded in. grid (16 ktiles, 48 sel*h).
__global__ __launch_bounds__(256)
void convert_wqkv(const float* __restrict__ Wq, const float* __restrict__ Wk,
                  const float* __restrict__ Wv, ushort* __restrict__ Wt) {
  __shared__ ushort T[64 * 72];
  const int tid = threadIdx.x;
  const int kt = blockIdx.x, sh = blockIdx.y;
  const int sel = sh >> 4, h = sh & 15;
  const float* W = (sel == 0) ? Wq : ((sel == 1) ? Wk : Wv);
  const float qs = (sel == 0) ? QSCALE : 1.0f;
  const int rr = tid >> 4;          // 0..15 (k' row)
  const int rc = (tid & 15) * 4;    // d col (float4)
#pragma unroll
  for (int p = 0; p < 64; p += 16) {
    const float4 f = *(const float4*)(W + (size_t)h * 65536 + (size_t)(kt * 64 + p + rr) * 64 + rc);
    ushort4 u;
    u.x = f2b(f.x * qs); u.y = f2b(f.y * qs); u.z = f2b(f.z * qs); u.w = f2b(f.w * qs);
    *(ushort4*)&T[(p + rr) * 72 + rc] = u;
  }
  __syncthreads();
  const int dd = tid >> 2;          // 0..63 (d)
  const int c16 = (tid & 3) * 16;   // k' base
  sh8 v0, v1;
#pragma unroll
  for (int j = 0; j < 8; j++) v0[j] = (short)T[(c16 + j) * 72 + dd];
#pragma unroll
  for (int j = 0; j < 8; j++) v1[j] = (short)T[(c16 + 8 + j) * 72 + dd];
  ushort* op = Wt + ((size_t)sel * 1024 + h * 64 + dd) * 1024 + kt * 64 + c16;
  *(sh8*)op = v0;
  *(sh8*)(op + 8) = v1;
}

// ---------------- GEMM: 128x128 block, 64x64 wave tile (2x2 of 32x32 MFMA),
// BK=64, XOR-swizzled LDS, C^T epilogue. acc = 64 regs/wave (occupancy-safe).
// MODE 0: store bf16.  MODE 1: store f32 + bias.
template <int MODE>
__global__ __launch_bounds__(256)
void gemm_bt(const ushort* __restrict__ A, const ushort* __restrict__ Bt,
             ushort* __restrict__ Cb, float* __restrict__ Cf,
             const float* __restrict__ bias, int M, int N, int K) {
  __shared__ ushort Al[128 * 64];   // 16 KB
  __shared__ ushort Bl[128 * 64];   // 16 KB
  const int tid = threadIdx.x;
  const int lane = tid & 63, w = tid >> 6;
  const int l31 = lane & 31, hw = lane >> 5;
  const int wm = (w >> 1) * 64, wn = (w & 1) * 64;
  const int m0 = blockIdx.y * 128, n0 = blockIdx.x * 128;

  f32x16 acc[2][2];
#pragma unroll
  for (int i = 0; i < 2; i++)
#pragma unroll
    for (int j = 0; j < 2; j++)
#pragma unroll
      for (int r = 0; r < 16; r++) acc[i][j][r] = 0.f;

  // staging: unit u covers LDS ushorts [u*8, u*8+8); row=u>>3, cc=u&7 (swizzled)
  const int rbase = tid >> 3;                         // 0..31
  const int swzc = ((tid & 7) ^ (rbase & 7)) * 8;     // swizzled source col (ushorts)
  const ushort* Ag[4]; const ushort* Bg[4];
  ushort* lA[4]; ushort* lB[4];
#pragma unroll
  for (int i = 0; i < 4; i++) {
    Ag[i] = A + (size_t)min(m0 + i * 32 + rbase, M - 1) * K + swzc;
    Bg[i] = Bt + (size_t)(n0 + i * 32 + rbase) * K + swzc;
    lA[i] = &Al[(i * 256 + tid) * 8];
    lB[i] = &Bl[(i * 256 + tid) * 8];
  }
  // frag-read chunk offsets: k-chunk (ks*2+hw) un-swizzled by row's l31&7
  const int swz = l31 & 7;
  int ck[4];
#pragma unroll
  for (int ks = 0; ks < 4; ks++) ck[ks] = ((ks * 2 + hw) ^ swz) * 8;

  for (int k0 = 0; k0 < K; k0 += 64) {
    __syncthreads();
#pragma unroll
    for (int i = 0; i < 4; i++) {
      gld16(Ag[i] + k0, lA[i]);
      gld16(Bg[i] + k0, lB[i]);
    }
    __syncthreads();
#pragma unroll
    for (int ks = 0; ks < 4; ks++) {
      sh8 af[2], bf[2];
#pragma unroll
      for (int i = 0; i < 2; i++) af[i] = *(const sh8*)&Al[(wm + i * 32 + l31) * 64 + ck[ks]];
#pragma unroll
      for (int j = 0; j < 2; j++) bf[j] = *(const sh8*)&Bl[(wn + j * 32 + l31) * 64 + ck[ks]];
      // C^T: D[m=Ccol][n=Crow]; A-op = B-tile frag, B-op = A-tile frag
#pragma unroll
      for (int i = 0; i < 2; i++)
#pragma unroll
        for (int j = 0; j < 2; j++) acc[i][j] = MFMA32(bf[j], af[i], acc[i][j]);
    }
  }

  // C^T epilogue (32x32 C/D map: col=lane&31, row=(reg&3)+8*(reg>>2)+4*hw):
  // lane holds C-row = m0+wm+i*32+l31; C-cols = n0+wn+j*32 + rg*8 + hw*4 + 0..3
#pragma unroll
  for (int i = 0; i < 2; i++) {
    const int row = m0 + wm + i * 32 + l31;
    const bool ok = row < M;
#pragma unroll
    for (int j = 0; j < 2; j++) {
#pragma unroll
      for (int rg = 0; rg < 4; rg++) {
        const int col0 = n0 + wn + j * 32 + rg * 8 + hw * 4;
        if (MODE == 0) {
          uint2 pk;
          pk.x = pk_bf16(acc[i][j][rg * 4 + 0], acc[i][j][rg * 4 + 1]);
          pk.y = pk_bf16(acc[i][j][rg * 4 + 2], acc[i][j][rg * 4 + 3]);
          if (ok) *(uint2*)&Cb[(size_t)row * N + col0] = pk;
        } else {
          const float4 b4 = *(const float4*)&bias[col0];
          float4 v;
          v.x = acc[i][j][rg * 4 + 0] + b4.x; v.y = acc[i][j][rg * 4 + 1] + b4.y;
          v.z = acc[i][j][rg * 4 + 2] + b4.z; v.w = acc[i][j][rg * 4 + 3] + b4.w;
          if (ok) *(float4*)&Cf[(size_t)row * N + col0] = v;
        }
      }
    }
  }
}

// ---------------- transpose V: QKV[.,2048+h*64+d] -> Vt[(bh*64+d)][s], zero-padded ----------------
__global__ __launch_bounds__(256)
void transpose_v(const ushort* __restrict__ QKV, ushort* __restrict__ Vtg) {
  __shared__ ushort T[64 * 72];
  const int tid = threadIdx.x;
  const int st = blockIdx.x, bh = blockIdx.y;
  const int b = bh >> 4, h = bh & 15;
  const int sr = tid >> 3;          // 0..31
  const int sc = (tid & 7) * 8;     // d-chunk
#pragma unroll
  for (int p = 0; p < 64; p += 32) {
    const int s = st * 64 + p + sr;
    uint4 d = uint4{0u, 0u, 0u, 0u};
    if (s < SS) d = *(const uint4*)(QKV + ((size_t)b * SS + s) * 3072 + 2048 + h * 64 + sc);
    *(uint4*)&T[(p + sr) * 72 + sc] = d;
  }
  __syncthreads();
  const int dd = tid >> 2;          // 0..63
  const int s16 = (tid & 3) * 16;
  sh8 v0, v1;
#pragma unroll
  for (int j = 0; j < 8; j++) v0[j] = (short)T[(s16 + j) * 72 + dd];
#pragma unroll
  for (int j = 0; j < 8; j++) v1[j] = (short)T[(s16 + 8 + j) * 72 + dd];
  ushort* outp = Vtg + ((size_t)bh * 64 + dd) * SPAD + st * 64 + s16;
  *(sh8*)outp = v0;
  *(sh8*)(outp + 8) = v1;
}

// ---------------- flash attention (one-pass softmax, 32 q-rows/wave) -------------
// grid: (5 qblocks of 128, 512 bh). K/V staged via gld16 into swizzled 64-stride
// tiles; each wave reuses K/V frags across 2 q-groups of 16.
// S^T = K·Q^T; O^T = V^T·P^T; l = ones·P^T (all MFMA, no shuffles).
__global__ __launch_bounds__(256)
void flash_attn(const ushort* __restrict__ QKV, const ushort* __restrict__ Vtg,
                ushort* __restrict__ Ob) {
  __shared__ ushort Kl[64 * 64];    // row = kpos, chunk-swizzled
  __shared__ ushort Vl[64 * 64];    // row = d,    chunk-swizzled
  __shared__ ushort Pl[128 * 72];   // row = q (wave-local 32 rows), col = kpos
  const int tid = threadIdx.x;
  const int lane = tid & 63, w = tid >> 6;
  const int l15 = lane & 15, quad = lane >> 4;
  const int qb = blockIdx.x, bh = blockIdx.y;
  const int b = bh >> 4, h = bh & 15;

  sh8 qf[2][2];
#pragma unroll
  for (int g = 0; g < 2; g++) {
    const int qr = qb * 128 + w * 32 + g * 16 + l15;
    const ushort* qrow = QKV + ((size_t)b * SS + min(qr, SS - 1)) * 3072 + h * 64;
    qf[g][0] = *(const sh8*)(qrow + quad * 8);
    qf[g][1] = *(const sh8*)(qrow + 32 + quad * 8);
  }

  sh8 ones;
#pragma unroll
  for (int j = 0; j < 8; j++) ones[j] = (short)0x3F80;   // bf16 1.0

  f32x4 o[2][4];
  f32x4 acc_l[2];
#pragma unroll
  for (int g = 0; g < 2; g++) {
    acc_l[g] = f32x4{0.f, 0.f, 0.f, 0.f};
#pragma unroll
    for (int t = 0; t < 4; t++) o[g][t] = f32x4{0.f, 0.f, 0.f, 0.f};
  }

  // staging: 2 gld16 per matrix; unit u = i*256+tid, row=u>>3, cc=u&7, swizzled source
  const int r0 = tid >> 3;                           // 0..31
  const int swzs = ((tid & 7) ^ (r0 & 7)) * 8;
  const ushort* Kg = QKV + (size_t)b * SS * 3072 + 1024 + h * 64 + swzs;
  const ushort* Vg0 = Vtg + ((size_t)bh * 64 + r0) * SPAD + swzs;
  const ushort* Vg1 = Vtg + ((size_t)bh * 64 + 32 + r0) * SPAD + swzs;
  ushort* lK0 = &Kl[tid * 8];
  ushort* lK1 = &Kl[(256 + tid) * 8];
  ushort* lV0 = &Vl[tid * 8];
  ushort* lV1 = &Vl[(256 + tid) * 8];

  const int swz = l15 & 7;
  const int ca0 = (quad ^ swz) * 8;
  const int ca1 = ((quad + 4) ^ swz) * 8;
  ushort* plw[2] = { &Pl[(w * 32 + l15) * 72], &Pl[(w * 32 + 16 + l15) * 72] };

  for (int kt = 0; kt < 10; kt++) {
    const int kb = kt * 64;
    __syncthreads();
    gld16(Kg + (size_t)min(kb + r0, SS - 1) * 3072, lK0);
    gld16(Kg + (size_t)min(kb + 32 + r0, SS - 1) * 3072, lK1);
    gld16(Vg0 + kb, lV0);
    gld16(Vg1 + kb, lV1);
    __syncthreads();

#pragma unroll
    for (int tn = 0; tn < 4; tn++) {
      const int kr = tn * 16 + l15;
      const sh8 k0 = *(const sh8*)&Kl[kr * 64 + ca0];
      const sh8 k1 = *(const sh8*)&Kl[kr * 64 + ca1];
#pragma unroll
      for (int g = 0; g < 2; g++) {
        f32x4 s = f32x4{0.f, 0.f, 0.f, 0.f};
        s = MFMA16(k0, qf[g][0], s);      // S^T: row=kpos=tn*16+quad*4+r, col=q=l15
        s = MFMA16(k1, qf[g][1], s);
        if (kt == 9) {                    // kb=576: only kpos-local 0 is valid
#pragma unroll
          for (int r = 0; r < 4; r++)
            if ((tn * 16 + quad * 4 + r) != 0) s[r] = -1e30f;
        }
        uint2 pp;
        pp.x = pk_bf16(EXP2F(s[0]), EXP2F(s[1]));
        pp.y = pk_bf16(EXP2F(s[2]), EXP2F(s[3]));
        *(uint2*)(plw[g] + tn * 16 + quad * 4) = pp;
      }
    }
    // wave-local P rows: no barrier needed between write and read
    sh8 pa[2][2];
#pragma unroll
    for (int g = 0; g < 2; g++) {
      pa[g][0] = *(const sh8*)(plw[g] + quad * 8);     // B: n=q=l15, k=kpos
      pa[g][1] = *(const sh8*)(plw[g] + 32 + quad * 8);
      acc_l[g] = MFMA16(ones, pa[g][0], acc_l[g]);
      acc_l[g] = MFMA16(ones, pa[g][1], acc_l[g]);
    }
#pragma unroll
    for (int t = 0; t < 4; t++) {
      const int vr = t * 16 + l15;
      const sh8 v0 = *(const sh8*)&Vl[vr * 64 + ca0];  // A: m=d, k=kpos
      const sh8 v1 = *(const sh8*)&Vl[vr * 64 + ca1];
#pragma unroll
      for (int g = 0; g < 2; g++) {
        o[g][t] = MFMA16(v0, pa[g][0], o[g][t]);       // O^T: row=d, col=q=l15
        o[g][t] = MFMA16(v1, pa[g][1], o[g][t]);
      }
    }
  }

#pragma unroll
  for (int g = 0; g < 2; g++) {
    const float inv = 1.0f / acc_l[g][0];
    const int s = qb * 128 + w * 32 + g * 16 + l15;
    if (s < SS) {
      ushort* op = Ob + ((size_t)b * SS + s) * 1024 + h * 64 + quad * 4;
#pragma unroll
      for (int t = 0; t < 4; t++) {
        uint2 ov;
        ov.x = pk_bf16(o[g][t][0] * inv, o[g][t][1] * inv);
        ov.y = pk_bf16(o[g][t][2] * inv, o[g][t][3] * inv);
        *(uint2*)(op + t * 16) = ov;
      }
    }
  }
}

// ---------------- launch ----------------
extern "C" void kernel_launch(void* const* d_in, const int* in_sizes, int n_in,
                              void* d_out, int out_size, void* d_ws, size_t ws_size,
                              hipStream_t stream) {
  const float* x  = (const float*)d_in[0];
  const float* Wq = (const float*)d_in[1];
  const float* Wk = (const float*)d_in[2];
  const float* Wv = (const float*)d_in[3];
  const float* Wo = (const float*)d_in[4];
  const float* bo = (const float*)d_in[5];
  float* out = (float*)d_out;

  // workspace layout (bf16 elements); Ob reuses Xb (dead after GEMM1)
  ushort* Xb  = (ushort*)d_ws;                      // MM*1024
  ushort* Wt  = Xb  + (size_t)MM * 1024;            // 3072*1024
  ushort* Wob = Wt  + (size_t)3072 * 1024;          // 1024*1024
  ushort* QKV = Wob + (size_t)1024 * 1024;          // MM*3072
  ushort* Vtg = QKV + (size_t)MM * 3072;            // 512*64*640
  ushort* Ob  = Xb;

  convert2_f32_bf16<<<4096, 256, 0, stream>>>(x, Xb, MM * 1024 / 4, Wo, Wob, 1024 * 1024 / 4);
  convert_wqkv<<<dim3(16, 48), 256, 0, stream>>>(Wq, Wk, Wv, Wt);
  gemm_bt<0><<<dim3(24, 145), 256, 0, stream>>>(Xb, Wt, QKV, nullptr, nullptr, MM, 3072, 1024);
  transpose_v<<<dim3(10, 512), 256, 0, stream>>>(QKV, Vtg);
  flash_attn<<<dim3(5, 512), 256, 0, stream>>>(QKV, Vtg, Ob);
  gemm_bt<1><<<dim3(8, 145), 256, 0, stream>>>(Ob, Wob, nullptr, out, bo, MM, 1024, 1024);
}